// Round 4
// baseline (2526.472 us; speedup 1.0000x reference)
//
#include <hip/hip_runtime.h>
#include <cstdint>
#include <cstddef>

// ---------------------------------------------------------------------------
// BasicVQVAE forward. Round 5:
//  - R4 post-mortem: enc1 is pinned at the m97 2-barrier structure ceiling
//    (~950 TF eff, MfmaUtil 44). VALU-split removal was off-critical-path.
//  - This round: enc1 -> deep-pipelined schedule (T3+T4+T5):
//    256x128 tile, BK=32, 8 waves (4Mx2N), TRIPLE-buffered LDS (3x48 KiB),
//    4 phases/K-tile {ds_read | gload_lds issue | barrier | lgkmcnt(0) |
//    setprio+12 MFMA | barrier}, counted vmcnt(6) once per tile (never 0).
//    Chunk-major [kq][row] LDS layout -> stride-16B ds_read (2-way = free)
//    and trivial linear gload_lds staging. Bit-identical accumulation order.
//  - All other kernels unchanged from the 2209/2286-us passing versions.
// B=8192, X=4096, H=4096, Z=512, E=512, K_codes=8192.
// ---------------------------------------------------------------------------

#define BM 128
#define BN 128
#define BKT 16
#define LDA 132
#define LDB 132

typedef _Float16 half_t;
typedef __attribute__((ext_vector_type(8))) _Float16 f16x8;
typedef __attribute__((ext_vector_type(4))) _Float16 f16x4;
typedef __attribute__((ext_vector_type(4))) float floatx4;
typedef __attribute__((ext_vector_type(8))) short bf16x8;

#define LO_SCALE 4096.f            // 2^12
#define LO_INV   2.44140625e-4f    // 2^-12

__device__ __forceinline__ short f2bf(float v) {
    union { float f; unsigned u; } x; x.f = v;
    unsigned r = x.u + 0x7fff + ((x.u >> 16) & 1);   // round-to-nearest-even
    return (short)(r >> 16);
}

__device__ __forceinline__ void gload16(const void* g, void* l) {
    __builtin_amdgcn_global_load_lds(
        (const __attribute__((address_space(1))) void*)(uintptr_t)g,
        (__attribute__((address_space(3))) void*)(uintptr_t)l,
        16, 0, 0);
}

__device__ __forceinline__ void fsplit(float v, half_t& hi, half_t& lo) {
    hi = (half_t)v;
    lo = (half_t)((v - (float)hi) * LO_SCALE);
}

#define MFMA16F(a, b, c) __builtin_amdgcn_mfma_f32_16x16x32_f16((a), (b), (c), 0, 0, 0)

#define SBARRIER() do { \
    __builtin_amdgcn_sched_barrier(0); \
    __builtin_amdgcn_s_barrier(); \
    __builtin_amdgcn_sched_barrier(0); \
} while (0)

#define LGKM0() do { \
    asm volatile("s_waitcnt lgkmcnt(0)" ::: "memory"); \
    __builtin_amdgcn_sched_barrier(0); \
} while (0)

// ============================ fp32 GEMM (enc3 only) ========================
__global__ __launch_bounds__(256, 2)
void gemm_bias_act(const float* __restrict__ A, const float* __restrict__ B,
                   const float* __restrict__ bias, float* __restrict__ C,
                   int M, int N, int K, int relu)
{
    __shared__ float as[BKT][LDA];   // as[k][m]
    __shared__ float bs[BKT][LDB];   // bs[k][n]
    const int tid = threadIdx.x;
    const int tx = tid & 15;
    const int ty = tid >> 4;
    const int row0 = blockIdx.y * BM;
    const int col0 = blockIdx.x * BN;

    const int ar = tid >> 2;             // 0..63
    const int ac = (tid & 3) << 2;       // 0,4,8,12
    const int br = tid >> 5;             // 0..7
    const int bc = (tid & 31) << 2;      // 0..124

    const float* Ap0 = A + (size_t)(row0 + ar) * K + ac;
    const float* Ap1 = A + (size_t)(row0 + ar + 64) * K + ac;
    const float* Bp0 = B + (size_t)br * N + col0 + bc;
    const float* Bp1 = B + (size_t)(br + 8) * N + col0 + bc;

    float acc[8][8];
#pragma unroll
    for (int i = 0; i < 8; ++i)
#pragma unroll
        for (int j = 0; j < 8; ++j) acc[i][j] = 0.f;

    for (int k0 = 0; k0 < K; k0 += BKT) {
        float4 a0 = *(const float4*)(Ap0 + k0);
        float4 a1 = *(const float4*)(Ap1 + k0);
        float4 b0 = *(const float4*)(Bp0 + (size_t)k0 * N);
        float4 b1 = *(const float4*)(Bp1 + (size_t)k0 * N);
        __syncthreads();
        as[ac + 0][ar] = a0.x; as[ac + 1][ar] = a0.y;
        as[ac + 2][ar] = a0.z; as[ac + 3][ar] = a0.w;
        as[ac + 0][ar + 64] = a1.x; as[ac + 1][ar + 64] = a1.y;
        as[ac + 2][ar + 64] = a1.z; as[ac + 3][ar + 64] = a1.w;
        *(float4*)&bs[br][bc] = b0;
        *(float4*)&bs[br + 8][bc] = b1;
        __syncthreads();
#pragma unroll
        for (int k = 0; k < BKT; ++k) {
            float af[8], bf0[4], bf1[4];
            *(float4*)&af[0] = *(const float4*)&as[k][ty * 8];
            *(float4*)&af[4] = *(const float4*)&as[k][ty * 8 + 4];
            *(float4*)&bf0[0] = *(const float4*)&bs[k][tx * 4];
            *(float4*)&bf1[0] = *(const float4*)&bs[k][64 + tx * 4];
#pragma unroll
            for (int i = 0; i < 8; ++i) {
#pragma unroll
                for (int j = 0; j < 4; ++j) {
                    acc[i][j]     = fmaf(af[i], bf0[j], acc[i][j]);
                    acc[i][j + 4] = fmaf(af[i], bf1[j], acc[i][j + 4]);
                }
            }
        }
    }

    float bv0[4], bv1[4];
#pragma unroll
    for (int j = 0; j < 4; ++j) {
        bv0[j] = bias[col0 + tx * 4 + j];
        bv1[j] = bias[col0 + 64 + tx * 4 + j];
    }
#pragma unroll
    for (int i = 0; i < 8; ++i) {
        const int row = row0 + ty * 8 + i;
        float4 o0, o1;
        o0.x = acc[i][0] + bv0[0]; o0.y = acc[i][1] + bv0[1];
        o0.z = acc[i][2] + bv0[2]; o0.w = acc[i][3] + bv0[3];
        o1.x = acc[i][4] + bv1[0]; o1.y = acc[i][5] + bv1[1];
        o1.z = acc[i][6] + bv1[2]; o1.w = acc[i][7] + bv1[3];
        if (relu) {
            o0.x = fmaxf(o0.x, 0.f); o0.y = fmaxf(o0.y, 0.f);
            o0.z = fmaxf(o0.z, 0.f); o0.w = fmaxf(o0.w, 0.f);
            o1.x = fmaxf(o1.x, 0.f); o1.y = fmaxf(o1.y, 0.f);
            o1.z = fmaxf(o1.z, 0.f); o1.w = fmaxf(o1.w, 0.f);
        }
        *(float4*)(C + (size_t)row * N + col0 + tx * 4) = o0;
        *(float4*)(C + (size_t)row * N + col0 + 64 + tx * 4) = o1;
    }
}

// ============================ VQ helpers ===================================
__global__ void cnorm_kernel(const float* __restrict__ CB, float* __restrict__ cnorm, int E)
{
    const int j = blockIdx.x;
    const float* c = CB + (size_t)j * E;
    float s = 0.f;
    for (int e = threadIdx.x; e < E; e += 64) { float v = c[e]; s += v * v; }
#pragma unroll
    for (int off = 32; off; off >>= 1) s += __shfl_down(s, off);
    if (threadIdx.x == 0) cnorm[j] = s;
}

__global__ void argmin_reduce(const float* __restrict__ partv, const int* __restrict__ parti,
                              int* __restrict__ idx, int M, int P)
{
    const int m = blockIdx.x * blockDim.x + threadIdx.x;
    if (m >= M) return;
    const float* pv = partv + (size_t)m * P;
    const int* pi = parti + (size_t)m * P;
    float best = pv[0]; int bi = pi[0];
    for (int t = 1; t < P; ++t) {
        float v = pv[t]; int ii = pi[t];
        if (v < best || (v == best && ii < bi)) { best = v; bi = ii; }
    }
    idx[m] = bi;
}

__global__ __launch_bounds__(256)
void vq_stats(const float* __restrict__ ZE, const float* __restrict__ CB,
              const int* __restrict__ idx, int* __restrict__ counts,
              float* __restrict__ vqaccum, int E)
{
    const int i = blockIdx.x;
    const int id = idx[i];
    const float* c = CB + (size_t)id * E;
    const float* z = ZE + (size_t)i * E;
    float s = 0.f;
    for (int e = threadIdx.x; e < E; e += 256) { float d = c[e] - z[e]; s += d * d; }
#pragma unroll
    for (int off = 32; off; off >>= 1) s += __shfl_down(s, off);
    __shared__ float red[4];
    const int lane = threadIdx.x & 63, w = threadIdx.x >> 6;
    if (lane == 0) red[w] = s;
    __syncthreads();
    if (threadIdx.x == 0) {
        atomicAdd(vqaccum, red[0] + red[1] + red[2] + red[3]);
        atomicAdd(counts + id, 1);
    }
}

__global__ void zero_kernel(int* __restrict__ p, int n)
{
    const int i = blockIdx.x * 256 + threadIdx.x;
    if (i < n) p[i] = 0;
}

__global__ __launch_bounds__(256)
void finalize(const int* __restrict__ counts, const float* __restrict__ vqaccum,
              float* __restrict__ tail, int NCODE, float invB, float scale)
{
    float s = 0.f;
    for (int j = threadIdx.x; j < NCODE; j += 256) {
        float p = (float)counts[j] * invB;
        s += p * logf(p + 1e-10f);
    }
#pragma unroll
    for (int off = 32; off; off >>= 1) s += __shfl_down(s, off);
    __shared__ float red[4];
    const int lane = threadIdx.x & 63, w = threadIdx.x >> 6;
    if (lane == 0) red[w] = s;
    __syncthreads();
    if (threadIdx.x == 0) {
        tail[0] = vqaccum[0] * scale;
        tail[1] = expf(-(red[0] + red[1] + red[2] + red[3]));
    }
}

// ============================ conversions ==================================
__global__ __launch_bounds__(256)
void transpose_bf16(const float* __restrict__ src, short* __restrict__ dst,
                    int Kd, int Nd)
{
    __shared__ float tile[32][33];
    const int bx = blockIdx.x * 32;   // N
    const int by = blockIdx.y * 32;   // K
    const int tx = threadIdx.x & 31, ty = threadIdx.x >> 5;
#pragma unroll
    for (int i = ty; i < 32; i += 8)
        tile[i][tx] = src[(size_t)(by + i) * Nd + bx + tx];
    __syncthreads();
#pragma unroll
    for (int i = ty; i < 32; i += 8)
        dst[(size_t)(bx + i) * Kd + by + tx] = f2bf(tile[tx][i]);
}

__global__ __launch_bounds__(256)
void transpose_split2(const float* __restrict__ src, half_t* __restrict__ dh,
                      half_t* __restrict__ dl, int Kd, int Nd)
{
    __shared__ float tile[32][33];
    const int bx = blockIdx.x * 32;   // N
    const int by = blockIdx.y * 32;   // K
    const int tx = threadIdx.x & 31, ty = threadIdx.x >> 5;
#pragma unroll
    for (int i = ty; i < 32; i += 8)
        tile[i][tx] = src[(size_t)(by + i) * Nd + bx + tx];
    __syncthreads();
#pragma unroll
    for (int i = ty; i < 32; i += 8) {
        float v = tile[tx][i];
        half_t h, l; fsplit(v, h, l);
        dh[(size_t)(bx + i) * Kd + by + tx] = h;
        dl[(size_t)(bx + i) * Kd + by + tx] = l;
    }
}

__global__ void convert_bf16_vec(const float* __restrict__ src, short* __restrict__ dst, int n4)
{
    const int i = blockIdx.x * 256 + threadIdx.x;
    if (i >= n4) return;
    float4 v = ((const float4*)src)[i];
    short4 o;
    o.x = f2bf(v.x); o.y = f2bf(v.y); o.z = f2bf(v.z); o.w = f2bf(v.w);
    ((short4*)dst)[i] = o;
}

__global__ void split2_vec(const float* __restrict__ src, half_t* __restrict__ hi,
                           half_t* __restrict__ lo, int n4)
{
    const int i = blockIdx.x * 256 + threadIdx.x;
    if (i >= n4) return;
    float4 v = ((const float4*)src)[i];
    f16x4 h, l;
    h[0] = (half_t)v.x; l[0] = (half_t)((v.x - (float)h[0]) * LO_SCALE);
    h[1] = (half_t)v.y; l[1] = (half_t)((v.y - (float)h[1]) * LO_SCALE);
    h[2] = (half_t)v.z; l[2] = (half_t)((v.z - (float)h[2]) * LO_SCALE);
    h[3] = (half_t)v.w; l[3] = (half_t)((v.w - (float)h[3]) * LO_SCALE);
    ((f16x4*)hi)[i] = h;
    ((f16x4*)lo)[i] = l;
}

// =================== enc1: deep-pipelined Dekker GEMM ======================
// C = relu(A[M,K] @ BT[N,K]^T + bias), A/B as f16 Dekker limb planes.
// 256x128 tile, BK=32, 512 thr = 8 waves (4M x 2N, 64x64 out each).
// Triple-buffered LDS (3 x 48 KiB). Chunk-major [kq][row] layout: staging is
// linear (chunk = tid), ds_read_b128 is stride-16B (2-way aliasing = free).
// 4 phases per K-tile; counted vmcnt(6) once per tile (prefetch depth 2).
// Accumulation order identical to the 2-phase version -> bit-identical out.
#define E1_BUF 49152            // 48 KiB per buffer
#define E1_AH  0                // A-hi  region: 16 KiB (256 rows x 4 kq)
#define E1_AL  16384            // A-lo
#define E1_BH  32768            // B-hi  region: 8 KiB (128 rows x 4 kq)
#define E1_BL  40960            // B-lo

__global__ __launch_bounds__(512, 2)
void enc1_8ph(const half_t* __restrict__ Ah, const half_t* __restrict__ Al,
              const half_t* __restrict__ Bh, const half_t* __restrict__ Bl,
              const float* __restrict__ bias,
              half_t* __restrict__ Ch, half_t* __restrict__ Cl,
              int N, int K)
{
    __shared__ char smem[3 * E1_BUF];   // 144 KiB
    const int t = threadIdx.x;          // 0..511
    const int lane = t & 63, wave = t >> 6;
    const int wm = wave >> 1;           // 0..3 (row quadrant, 64 rows)
    const int wn = wave & 1;            // 0..1 (col half, 64 cols)
    const int ml = lane & 15, quad = lane >> 4;
    const int row0 = blockIdx.y * 256, col0 = blockIdx.x * 128;

    // --- staging decode (chunk = linear 16B index; chunk = kq*ROWS + row) ---
    const int rowA = t & 255;
    const int kqA0 = t >> 8;                       // sweep0 kq: 0..1
    const int rowB = t & 127;
    const int kqB  = t >> 7;                       // 0..3
    const half_t* gAh0 = Ah + (size_t)(row0 + rowA) * K + kqA0 * 8;
    const half_t* gAh1 = gAh0 + 16;                // sweep1: kq+2 -> +16 elems
    const half_t* gAl0 = Al + (size_t)(row0 + rowA) * K + kqA0 * 8;
    const half_t* gAl1 = gAl0 + 16;
    const half_t* gBhp = Bh + (size_t)(col0 + rowB) * K + kqB * 8;
    const half_t* gBlp = Bl + (size_t)(col0 + rowB) * K + kqB * 8;
    const int dA0 = t * 16;                        // LDS byte offset, sweep 0
    const int dA1 = (512 + t) * 16;                // sweep 1
    const int dB  = t * 16;

    // --- fragment read byte offsets (chunk = quad*ROWS + row) ---
    const int aoff = ((quad << 8) + wm * 64 + ml) * 16;   // + i*256 per i
    const int boff = ((quad << 7) + wn * 64 + ml) * 16;   // + j*256 per j

    floatx4 acc_h[4][4] = {};
    floatx4 acc_c[4][4] = {};

    const int NT = K >> 5;
    int ro = 0, mo = E1_BUF, wo = 2 * E1_BUF;      // read / landing / issue

    // --- prologue: stage tiles 0 (buf0) and 1 (buf1); 12 loads in flight ---
    {
        char* b0 = smem;
        char* b1 = smem + E1_BUF;
        gload16(gAh0, b0 + E1_AH + dA0);  gload16(gAh1, b0 + E1_AH + dA1);
        gload16(gAl0, b0 + E1_AL + dA0);  gload16(gAl1, b0 + E1_AL + dA1);
        gload16(gBhp, b0 + E1_BH + dB );  gload16(gBlp, b0 + E1_BL + dB );
        gload16(gAh0 + 32, b1 + E1_AH + dA0);  gload16(gAh1 + 32, b1 + E1_AH + dA1);
        gload16(gAl0 + 32, b1 + E1_AL + dA0);  gload16(gAl1 + 32, b1 + E1_AL + dA1);
        gload16(gBhp + 32, b1 + E1_BH + dB );  gload16(gBlp + 32, b1 + E1_BL + dB );
    }
    asm volatile("s_waitcnt vmcnt(6)" ::: "memory");   // tile-0 loads done
    SBARRIER();

    for (int kt = 0; kt < NT; ++kt) {
        const int stage = (kt + 2 < NT);
        const size_t ks = (size_t)(kt + 2) * 32;       // k offset for prefetch
        char* rb = smem + ro;
        char* wb = smem + wo;
        f16x8 bhf[4], blf[4], ahf, alf;

        // ---------------- phase 0: B(8) + A(i=0); stage A-hi pair ----------
#pragma unroll
        for (int j = 0; j < 4; ++j) {
            bhf[j] = *(const f16x8*)(rb + E1_BH + boff + j * 256);
            blf[j] = *(const f16x8*)(rb + E1_BL + boff + j * 256);
        }
        ahf = *(const f16x8*)(rb + E1_AH + aoff + 0 * 256);
        alf = *(const f16x8*)(rb + E1_AL + aoff + 0 * 256);
        if (stage) { gload16(gAh0 + ks, wb + E1_AH + dA0);
                     gload16(gAh1 + ks, wb + E1_AH + dA1); }
        SBARRIER(); LGKM0();
        __builtin_amdgcn_s_setprio(1);
#pragma unroll
        for (int j = 0; j < 4; ++j) acc_h[0][j] = MFMA16F(ahf, bhf[j], acc_h[0][j]);
#pragma unroll
        for (int j = 0; j < 4; ++j) acc_c[0][j] = MFMA16F(ahf, blf[j], acc_c[0][j]);
#pragma unroll
        for (int j = 0; j < 4; ++j) acc_c[0][j] = MFMA16F(alf, bhf[j], acc_c[0][j]);
        __builtin_amdgcn_s_setprio(0);
        SBARRIER();

        // ---------------- phase 1: A(i=1); stage A-lo pair -----------------
        ahf = *(const f16x8*)(rb + E1_AH + aoff + 1 * 256);
        alf = *(const f16x8*)(rb + E1_AL + aoff + 1 * 256);
        if (stage) { gload16(gAl0 + ks, wb + E1_AL + dA0);
                     gload16(gAl1 + ks, wb + E1_AL + dA1); }
        SBARRIER(); LGKM0();
        __builtin_amdgcn_s_setprio(1);
#pragma unroll
        for (int j = 0; j < 4; ++j) acc_h[1][j] = MFMA16F(ahf, bhf[j], acc_h[1][j]);
#pragma unroll
        for (int j = 0; j < 4; ++j) acc_c[1][j] = MFMA16F(ahf, blf[j], acc_c[1][j]);
#pragma unroll
        for (int j = 0; j < 4; ++j) acc_c[1][j] = MFMA16F(alf, bhf[j], acc_c[1][j]);
        __builtin_amdgcn_s_setprio(0);
        SBARRIER();

        // ---------------- phase 2: A(i=2); stage B pair --------------------
        ahf = *(const f16x8*)(rb + E1_AH + aoff + 2 * 256);
        alf = *(const f16x8*)(rb + E1_AL + aoff + 2 * 256);
        if (stage) { gload16(gBhp + ks, wb + E1_BH + dB);
                     gload16(gBlp + ks, wb + E1_BL + dB); }
        SBARRIER(); LGKM0();
        __builtin_amdgcn_s_setprio(1);
#pragma unroll
        for (int j = 0; j < 4; ++j) acc_h[2][j] = MFMA16F(ahf, bhf[j], acc_h[2][j]);
#pragma unroll
        for (int j = 0; j < 4; ++j) acc_c[2][j] = MFMA16F(ahf, blf[j], acc_c[2][j]);
#pragma unroll
        for (int j = 0; j < 4; ++j) acc_c[2][j] = MFMA16F(alf, bhf[j], acc_c[2][j]);
        __builtin_amdgcn_s_setprio(0);
        SBARRIER();

        // ---------------- phase 3: A(i=3); no stage ------------------------
        ahf = *(const f16x8*)(rb + E1_AH + aoff + 3 * 256);
        alf = *(const f16x8*)(rb + E1_AL + aoff + 3 * 256);
        SBARRIER(); LGKM0();
        __builtin_amdgcn_s_setprio(1);
#pragma unroll
        for (int j = 0; j < 4; ++j) acc_h[3][j] = MFMA16F(ahf, bhf[j], acc_h[3][j]);
#pragma unroll
        for (int j = 0; j < 4; ++j) acc_c[3][j] = MFMA16F(ahf, blf[j], acc_c[3][j]);
#pragma unroll
        for (int j = 0; j < 4; ++j) acc_c[3][j] = MFMA16F(alf, bhf[j], acc_c[3][j]);
        __builtin_amdgcn_s_setprio(0);

        // ---- tile end: own stage(kt+1) loads done, 6 (stage kt+2) in flight
        if (kt + 1 < NT) {
            if (stage) { asm volatile("s_waitcnt vmcnt(6)" ::: "memory"); }
            else       { asm volatile("s_waitcnt vmcnt(0)" ::: "memory"); }
            SBARRIER();
        }
        const int tmp = ro; ro = mo; mo = wo; wo = tmp;   // rotate buffers
    }

    // ---- epilogue: combine limbs, bias+ReLU, split-store (bit-identical) --
    float bv[4];
#pragma unroll
    for (int j = 0; j < 4; ++j) bv[j] = bias[col0 + wn * 64 + j * 16 + ml];
#pragma unroll
    for (int i = 0; i < 4; ++i) {
#pragma unroll
        for (int j = 0; j < 4; ++j) {
            const int col = col0 + wn * 64 + j * 16 + ml;
#pragma unroll
            for (int reg = 0; reg < 4; ++reg) {
                const int row = row0 + wm * 64 + i * 16 + quad * 4 + reg;
                float v = fmaf(acc_c[i][j][reg], LO_INV, acc_h[i][j][reg]) + bv[j];
                v = fmaxf(v, 0.f);
                half_t hh = (half_t)v;
                Ch[(size_t)row * N + col] = hh;
                Cl[(size_t)row * N + col] = (half_t)((v - (float)hh) * LO_SCALE);
            }
        }
    }
}

// ===================== double-f16 MFMA GEMM (m97 structure) ================
// MODE 0: fp32 out Cf (+bias). Used for enc2 (small K-extent output).
template<int MODE>
__global__ __launch_bounds__(256, 2)
void gemm_f16x2(const half_t* __restrict__ Ah, const half_t* __restrict__ Al,
                const half_t* __restrict__ Bh, const half_t* __restrict__ Bl,
                const float* __restrict__ bias, float* __restrict__ Cf,
                half_t* __restrict__ Ch, half_t* __restrict__ Cl,
                int N, int K)
{
    __shared__ half_t sAh[128 * 32], sAl[128 * 32], sBh[128 * 32], sBl[128 * 32];
    const int t = threadIdx.x;
    const int lane = t & 63, wave = t >> 6;
    const int rh = (wave >> 1) * 64, ch = (wave & 1) * 64;
    const int ml = lane & 15, quad = lane >> 4;
    const int row0 = blockIdx.y * 128, col0 = blockIdx.x * 128;

    const int r = t >> 2, c = t & 3;
    const half_t* pA0h = Ah + (size_t)(row0 + r) * K + c * 8;
    const half_t* pA1h = Ah + (size_t)(row0 + r + 64) * K + c * 8;
    const half_t* pA0l = Al + (size_t)(row0 + r) * K + c * 8;
    const half_t* pA1l = Al + (size_t)(row0 + r + 64) * K + c * 8;
    const half_t* pB0h = Bh + (size_t)(col0 + r) * K + c * 8;
    const half_t* pB1h = Bh + (size_t)(col0 + r + 64) * K + c * 8;
    const half_t* pB0l = Bl + (size_t)(col0 + r) * K + c * 8;
    const half_t* pB1l = Bl + (size_t)(col0 + r + 64) * K + c * 8;
    half_t* dA0h = sAh + (r * 4 + c) * 8;  half_t* dA1h = sAh + ((r + 64) * 4 + c) * 8;
    half_t* dA0l = sAl + (r * 4 + c) * 8;  half_t* dA1l = sAl + ((r + 64) * 4 + c) * 8;
    half_t* dB0h = sBh + (r * 4 + c) * 8;  half_t* dB1h = sBh + ((r + 64) * 4 + c) * 8;
    half_t* dB0l = sBl + (r * 4 + c) * 8;  half_t* dB1l = sBl + ((r + 64) * 4 + c) * 8;

    floatx4 acc_h[4][4] = {};
    floatx4 acc_c[4][4] = {};

    for (int k0 = 0; k0 < K; k0 += 32) {
        __syncthreads();
        gload16(pA0h + k0, dA0h); gload16(pA1h + k0, dA1h);
        gload16(pA0l + k0, dA0l); gload16(pA1l + k0, dA1l);
        gload16(pB0h + k0, dB0h); gload16(pB1h + k0, dB1h);
        gload16(pB0l + k0, dB0l); gload16(pB1l + k0, dB1l);
        __syncthreads();
        f16x8 ah[4], alo[4], bh[4], blo[4];
#pragma unroll
        for (int i = 0; i < 4; ++i) {
            ah[i]  = *(const f16x8*)(sAh + (rh + i * 16 + ml) * 32 + quad * 8);
            alo[i] = *(const f16x8*)(sAl + (rh + i * 16 + ml) * 32 + quad * 8);
        }
#pragma unroll
        for (int j = 0; j < 4; ++j) {
            bh[j]  = *(const f16x8*)(sBh + (ch + j * 16 + ml) * 32 + quad * 8);
            blo[j] = *(const f16x8*)(sBl + (ch + j * 16 + ml) * 32 + quad * 8);
        }
#pragma unroll
        for (int i = 0; i < 4; ++i)
#pragma unroll
            for (int j = 0; j < 4; ++j) {
                acc_h[i][j] = MFMA16F(ah[i],  bh[j],  acc_h[i][j]);
                acc_c[i][j] = MFMA16F(ah[i],  blo[j], acc_c[i][j]);
                acc_c[i][j] = MFMA16F(alo[i], bh[j],  acc_c[i][j]);
            }
    }

    float bv[4];
#pragma unroll
    for (int j = 0; j < 4; ++j) bv[j] = bias[col0 + ch + j * 16 + ml];
#pragma unroll
    for (int i = 0; i < 4; ++i)
#pragma unroll
        for (int j = 0; j < 4; ++j) {
            const int col = col0 + ch + j * 16 + ml;
#pragma unroll
            for (int reg = 0; reg < 4; ++reg) {
                const int row = row0 + rh + i * 16 + quad * 4 + reg;
                float v = fmaf(acc_c[i][j][reg], LO_INV, acc_h[i][j][reg]) + bv[j];
                if (MODE == 0) {
                    Cf[(size_t)row * N + col] = v;
                } else {
                    v = fmaxf(v, 0.f);
                    half_t hh = (half_t)v;
                    Ch[(size_t)row * N + col] = hh;
                    Cl[(size_t)row * N + col] = (half_t)((v - (float)hh) * LO_SCALE);
                }
            }
        }
}

// VQ distance + fused partial argmin. score_j = ||c_j||^2 - 2*(ze . c_j)
__global__ __launch_bounds__(256, 2)
void dist_f16x2_argmin(const half_t* __restrict__ Ah, const half_t* __restrict__ Al,
                       const half_t* __restrict__ Bh, const half_t* __restrict__ Bl,
                       const float* __restrict__ cnorm, float* __restrict__ partv,
                       int* __restrict__ parti, int K)
{
    __shared__ half_t smem[4 * 128 * 32];
    half_t* sAh = smem;
    half_t* sAl = smem + 4096;
    half_t* sBh = smem + 8192;
    half_t* sBl = smem + 12288;

    const int t = threadIdx.x;
    const int lane = t & 63, wave = t >> 6;
    const int rh = (wave >> 1) * 64, ch = (wave & 1) * 64;
    const int ml = lane & 15, quad = lane >> 4;
    const int row0 = blockIdx.y * 128, col0 = blockIdx.x * 128;

    const int r = t >> 2, c = t & 3;
    const half_t* pA0h = Ah + (size_t)(row0 + r) * K + c * 8;
    const half_t* pA1h = Ah + (size_t)(row0 + r + 64) * K + c * 8;
    const half_t* pA0l = Al + (size_t)(row0 + r) * K + c * 8;
    const half_t* pA1l = Al + (size_t)(row0 + r + 64) * K + c * 8;
    const half_t* pB0h = Bh + (size_t)(col0 + r) * K + c * 8;
    const half_t* pB1h = Bh + (size_t)(col0 + r + 64) * K + c * 8;
    const half_t* pB0l = Bl + (size_t)(col0 + r) * K + c * 8;
    const half_t* pB1l = Bl + (size_t)(col0 + r + 64) * K + c * 8;
    half_t* dA0h = sAh + (r * 4 + c) * 8;  half_t* dA1h = sAh + ((r + 64) * 4 + c) * 8;
    half_t* dA0l = sAl + (r * 4 + c) * 8;  half_t* dA1l = sAl + ((r + 64) * 4 + c) * 8;
    half_t* dB0h = sBh + (r * 4 + c) * 8;  half_t* dB1h = sBh + ((r + 64) * 4 + c) * 8;
    half_t* dB0l = sBl + (r * 4 + c) * 8;  half_t* dB1l = sBl + ((r + 64) * 4 + c) * 8;

    floatx4 acc_h[4][4] = {};
    floatx4 acc_c[4][4] = {};

    for (int k0 = 0; k0 < K; k0 += 32) {
        __syncthreads();
        gload16(pA0h + k0, dA0h); gload16(pA1h + k0, dA1h);
        gload16(pA0l + k0, dA0l); gload16(pA1l + k0, dA1l);
        gload16(pB0h + k0, dB0h); gload16(pB1h + k0, dB1h);
        gload16(pB0l + k0, dB0l); gload16(pB1l + k0, dB1l);
        __syncthreads();
        f16x8 ah[4], alo[4], bh[4], blo[4];
#pragma unroll
        for (int i = 0; i < 4; ++i) {
            ah[i]  = *(const f16x8*)(sAh + (rh + i * 16 + ml) * 32 + quad * 8);
            alo[i] = *(const f16x8*)(sAl + (rh + i * 16 + ml) * 32 + quad * 8);
        }
#pragma unroll
        for (int j = 0; j < 4; ++j) {
            bh[j]  = *(const f16x8*)(sBh + (ch + j * 16 + ml) * 32 + quad * 8);
            blo[j] = *(const f16x8*)(sBl + (ch + j * 16 + ml) * 32 + quad * 8);
        }
#pragma unroll
        for (int i = 0; i < 4; ++i)
#pragma unroll
            for (int j = 0; j < 4; ++j) {
                acc_h[i][j] = MFMA16F(ah[i],  bh[j],  acc_h[i][j]);
                acc_c[i][j] = MFMA16F(ah[i],  blo[j], acc_c[i][j]);
                acc_c[i][j] = MFMA16F(alo[i], bh[j],  acc_c[i][j]);
            }
    }

    float cnv[4];
#pragma unroll
    for (int j = 0; j < 4; ++j) cnv[j] = cnorm[col0 + ch + j * 16 + ml];

    __syncthreads();                   // alias staging LDS for the reduction
    float* rv = (float*)smem;          // [128][32]
    int*   ri = (int*)(smem + 8192);   // [128][32]
    const int slot = (wave & 1) * 16 + ml;

#pragma unroll
    for (int i = 0; i < 4; ++i) {
#pragma unroll
        for (int reg = 0; reg < 4; ++reg) {
            const int lr = rh + i * 16 + quad * 4 + reg;
            float best = __builtin_inff(); int bi = 0;
#pragma unroll
            for (int j = 0; j < 4; ++j) {   // cols ascend with j -> strict <
                float s = fmaf(acc_c[i][j][reg], LO_INV, acc_h[i][j][reg]);
                float v = cnv[j] - 2.f * s;
                if (v < best) { best = v; bi = col0 + ch + j * 16 + ml; }
            }
            rv[lr * 32 + slot] = best;
            ri[lr * 32 + slot] = bi;
        }
    }
    __syncthreads();
    if (t < 128) {
        float best = __builtin_inff(); int bi = 0x7fffffff;
        for (int s = 0; s < 32; ++s) {
            const int sl = (s + t) & 31;   // rotated -> conflict-free
            float v = rv[t * 32 + sl]; int ii = ri[t * 32 + sl];
            if (v < best || (v == best && ii < bi)) { best = v; bi = ii; }
        }
        partv[(size_t)(row0 + t) * gridDim.x + blockIdx.x] = best;
        parti[(size_t)(row0 + t) * gridDim.x + blockIdx.x] = bi;
    }
}

// ============================ bf16 MFMA GEMM (decoder) =====================
template<int RELU, int OUT_BF16, int GATHER>
__global__ __launch_bounds__(256)
void mfma_gemm_bt(const short* __restrict__ A, const short* __restrict__ BT,
                  const float* __restrict__ bias, float* __restrict__ Cf,
                  short* __restrict__ Cb, int M, int N, int K,
                  const int* __restrict__ rowidx)
{
    __shared__ short sA[128 * 32];
    __shared__ short sB[128 * 32];
    const int t = threadIdx.x;
    const int lane = t & 63;
    const int wave = t >> 6;
    const int rh = (wave >> 1) * 64;
    const int ch = (wave & 1) * 64;
    const int ml = lane & 15;
    const int quad = lane >> 4;
    const int row0 = blockIdx.y * 128, col0 = blockIdx.x * 128;

    const int r = t >> 2;
    const int c = t & 3;
    int ga0 = row0 + r, ga1 = row0 + r + 64;
    if (GATHER) { ga0 = rowidx[ga0]; ga1 = rowidx[ga1]; }
    const short* pA0 = A + (size_t)ga0 * K + c * 8;
    const short* pA1 = A + (size_t)ga1 * K + c * 8;
    const short* pB0 = BT + (size_t)(col0 + r) * K + c * 8;
    const short* pB1 = BT + (size_t)(col0 + r + 64) * K + c * 8;
    short* dA0 = sA + (r * 4 + c) * 8;
    short* dA1 = sA + ((r + 64) * 4 + c) * 8;
    short* dB0 = sB + (r * 4 + c) * 8;
    short* dB1 = sB + ((r + 64) * 4 + c) * 8;

    floatx4 acc[4][4] = {};

    for (int k0 = 0; k0 < K; k0 += 32) {
        __syncthreads();
        gload16(pA0 + k0, dA0);
        gload16(pA1 + k0, dA1);
        gload16(pB0 + k0, dB0);
        gload16(pB1 + k0, dB1);
        __syncthreads();
        bf16x8 af[4], bf[4];
#pragma unroll
        for (int i = 0; i < 4; ++i)
            af[i] = *(const bf16x8*)(sA + ((rh + i * 16 + ml) * 32 + quad * 8));
#pragma unroll
        for (int j = 0; j < 4; ++j)
            bf[j] = *(const bf16x8*)(sB + ((ch + j * 16 + ml) * 32 + quad * 8));
#pragma unroll
        for (int i = 0; i < 4; ++i)
#pragma unroll
            for (int j = 0; j < 4; ++j)
                acc[i][j] = __builtin_amdgcn_mfma_f32_16x16x32_bf16(
                    af[i], bf[j], acc[i][j], 0, 0, 0);
    }

    float bv[4];
#pragma unroll
    for (int j = 0; j < 4; ++j) bv[j] = bias[col0 + ch + j * 16 + ml];
#pragma unroll
    for (int i = 0; i < 4; ++i) {
#pragma unroll
        for (int j = 0; j < 4; ++j) {
            const int col = col0 + ch + j * 16 + ml;
#pragma unroll
            for (int reg = 0; reg < 4; ++reg) {
                const int row = row0 + rh + i * 16 + quad * 4 + reg;
                float v = acc[i][j][reg] + bv[j];
                if (RELU) v = fmaxf(v, 0.f);
                if (OUT_BF16) Cb[(size_t)row * N + col] = f2bf(v);
                else          Cf[(size_t)row * N + col] = v;
            }
        }
    }
}

// ============================ launch =======================================
extern "C" void kernel_launch(void* const* d_in, const int* in_sizes, int n_in,
                              void* d_out, int out_size, void* d_ws, size_t ws_size,
                              hipStream_t stream)
{
    const float* x      = (const float*)d_in[0];
    const float* enc_w1 = (const float*)d_in[1];
    const float* enc_b1 = (const float*)d_in[2];
    const float* enc_w2 = (const float*)d_in[3];
    const float* enc_b2 = (const float*)d_in[4];
    const float* pre_w  = (const float*)d_in[5];
    const float* pre_b  = (const float*)d_in[6];
    const float* cb     = (const float*)d_in[7];
    const float* dec_w1 = (const float*)d_in[8];
    const float* dec_b1 = (const float*)d_in[9];
    const float* dec_w2 = (const float*)d_in[10];
    const float* dec_b2 = (const float*)d_in[11];
    float* out = (float*)d_out;

    const int B = 8192, X = 4096, H = 4096, Z = 512, E = 512, NC = 8192;

    // Workspace map (peak 200 MiB) with lifetime aliasing (same as R4):
    //   [0,128Mi):    xh/xl (until enc1)   -> then z, ze, zeh/zel, cbh/cbl,
    //                                          hd_bf
    //   [128,192Mi):  w1Th/w1Tl (enc1)     -> then dw1T, dw2T, cb_bf
    //   [192,200Mi):  w2Th/w2Tl (enc2)     -> then cn, pv, pi, idx, cnt, vqa
    //   hhp/hlp (enc1 out, 128 MiB) live on d_out (dead until dec2 writes
    //   x_recon at the very end; enc1 fully rewrites before enc2 reads).
    char* w = (char*)d_ws;
    half_t* xh   = (half_t*)(w);                      // 64 MiB
    half_t* xl   = (half_t*)(w + 67108864ull);        // 64 MiB
    half_t* w1Th = (half_t*)(w + 134217728ull);       // 32 MiB
    half_t* w1Tl = (half_t*)(w + 167772160ull);       // 32 MiB
    half_t* w2Th = (half_t*)(w + 201326592ull);       // 4 MiB
    half_t* w2Tl = (half_t*)(w + 205520896ull);       // 4 MiB  (peak 200 MiB)

    half_t* hhp  = (half_t*)d_out;                    // 64 MiB (on out)
    half_t* hlp  = (half_t*)((char*)d_out + 67108864ull); // 64 MiB (on out)

    float*  z    = (float*)(w);                       // 16 MiB (post-enc1)
    float*  ze   = (float*)(w + 16777216ull);         // 16 MiB
    half_t* zeh  = (half_t*)(w + 33554432ull);        // 8 MiB
    half_t* zel  = (half_t*)(w + 41943040ull);        // 8 MiB
    half_t* cbh  = (half_t*)(w + 50331648ull);        // 8 MiB
    half_t* cbl  = (half_t*)(w + 58720256ull);        // 8 MiB  -> 64 MiB
    short*  hd_bf= (short*)(w + 67108864ull);         // 64 MiB (post-enc1, xl)

    short*  dw1T = (short*)(w + 134217728ull);        // 4 MiB (post-enc1, w1T)
    short*  dw2T = (short*)(w + 138412032ull);        // 32 MiB
    short*  cb_bf= (short*)(w + 171966464ull);        // 8 MiB -> ends 180 MiB

    float*  cn   = (float*)(w + 201326592ull);        // 32 KiB (post-enc2, w2T)
    float*  pv   = (float*)(w + 201359360ull);        // 2 MiB (B*64)
    int*    pi   = (int*)  (w + 203456512ull);        // 2 MiB
    int*    idx  = (int*)  (w + 205553664ull);        // 32 KiB
    int*    cnt  = (int*)  (w + 205586432ull);        // 32 KiB
    float*  vqa  = (float*)(w + 205619200ull);        // 4 B

    dim3 blk(256);

    // input/weight prep: transpose + f16 limb split
    split2_vec<<<(B * X / 4 + 255) / 256, blk, 0, stream>>>(x, xh, xl, B * X / 4);
    transpose_split2<<<dim3(H / 32, X / 32), blk, 0, stream>>>(enc_w1, w1Th, w1Tl, X, H);
    transpose_split2<<<dim3(Z / 32, H / 32), blk, 0, stream>>>(enc_w2, w2Th, w2Tl, H, Z);

    // encoder (double-f16 MFMA; fp32-class precision)
    // enc1: deep-pipelined 256x128 kernel (512 threads, 144 KiB LDS)
    enc1_8ph<<<dim3(H / 128, B / 256), dim3(512), 0, stream>>>(
        xh, xl, w1Th, w1Tl, enc_b1, hhp, hlp, H, X);
    gemm_f16x2<0><<<dim3(Z / 128, B / 128), blk, 0, stream>>>(
        hhp, hlp, w2Th, w2Tl, enc_b2, z, nullptr, nullptr, Z, H);
    gemm_bias_act<<<dim3(E / BN, B / BM), blk, 0, stream>>>(z, pre_w, pre_b, ze, B, E, Z, 0);

    // VQ (double-f16 distances, exact fp32 cnorm, fused partial argmin)
    split2_vec<<<(B * E / 4 + 255) / 256, blk, 0, stream>>>(ze, zeh, zel, B * E / 4);
    split2_vec<<<(NC * E / 4 + 255) / 256, blk, 0, stream>>>(cb, cbh, cbl, NC * E / 4);
    cnorm_kernel<<<NC, 64, 0, stream>>>(cb, cn, E);
    zero_kernel<<<(NC + 1 + 255) / 256, blk, 0, stream>>>(cnt, NC + 1);
    dist_f16x2_argmin<<<dim3(NC / 128, B / 128), blk, 0, stream>>>(
        zeh, zel, cbh, cbl, cn, pv, pi, E);
    argmin_reduce<<<B / 256, blk, 0, stream>>>(pv, pi, idx, B, NC / 128);
    vq_stats<<<B, blk, 0, stream>>>(ze, cb, idx, cnt, vqa, E);

    // decoder (bf16 MFMA); weight prep placed after enc2 so regions are free
    convert_bf16_vec<<<(NC * E / 4 + 255) / 256, blk, 0, stream>>>(cb, cb_bf, NC * E / 4);
    transpose_bf16<<<dim3(H / 32, E / 32), blk, 0, stream>>>(dec_w1, dw1T, E, H);
    transpose_bf16<<<dim3(X / 32, H / 32), blk, 0, stream>>>(dec_w2, dw2T, H, X);
    mfma_gemm_bt<1, 1, 1><<<dim3(H / 128, B / 128), blk, 0, stream>>>(
        cb_bf, dw1T, dec_b1, nullptr, hd_bf, B, H, E, idx);
    mfma_gemm_bt<0, 0, 0><<<dim3(X / 128, B / 128), blk, 0, stream>>>(
        hd_bf, dw2T, dec_b2, out, nullptr, B, X, H, nullptr);

    finalize<<<1, blk, 0, stream>>>(cnt, vqa, out + (out_size - 2), NC,
                                    1.f / (float)B, 1.25f / ((float)B * (float)E));
}

// Round 5
// 2192.755 us; speedup vs baseline: 1.1522x; 1.1522x over previous
//
#include <hip/hip_runtime.h>
#include <cstdint>
#include <cstddef>

// ---------------------------------------------------------------------------
// BasicVQVAE forward. Round 6:
//  - R5 post-mortem: deep-pipeline port regressed (1 block/CU killed the
//    cross-block overlap; exposed barriers). Reverted.
//  - This round: keep the verified 2-phase structure, halve barrier density
//    via BK=64 with SLICED LDS [2][128][32] (preserves the conflict-free
//    64B-row-stride read geometry + linear gload_lds dest; source address
//    carries the slice permutation). LDS 64 KiB -> still 2 blocks/CU.
//    Accumulation order k-ascending per acc -> bit-identical output.
//    Applied to gemm_f16x2 (enc1/enc2), dist_f16x2_argmin, mfma_gemm_bt.
// B=8192, X=4096, H=4096, Z=512, E=512, K_codes=8192.
// ---------------------------------------------------------------------------

#define BM 128
#define BN 128
#define BKT 16
#define LDA 132
#define LDB 132

typedef _Float16 half_t;
typedef __attribute__((ext_vector_type(8))) _Float16 f16x8;
typedef __attribute__((ext_vector_type(4))) _Float16 f16x4;
typedef __attribute__((ext_vector_type(4))) float floatx4;
typedef __attribute__((ext_vector_type(8))) short bf16x8;

#define LO_SCALE 4096.f            // 2^12
#define LO_INV   2.44140625e-4f    // 2^-12

__device__ __forceinline__ short f2bf(float v) {
    union { float f; unsigned u; } x; x.f = v;
    unsigned r = x.u + 0x7fff + ((x.u >> 16) & 1);   // round-to-nearest-even
    return (short)(r >> 16);
}

__device__ __forceinline__ void gload16(const void* g, void* l) {
    __builtin_amdgcn_global_load_lds(
        (const __attribute__((address_space(1))) void*)(uintptr_t)g,
        (__attribute__((address_space(3))) void*)(uintptr_t)l,
        16, 0, 0);
}

__device__ __forceinline__ void fsplit(float v, half_t& hi, half_t& lo) {
    hi = (half_t)v;
    lo = (half_t)((v - (float)hi) * LO_SCALE);
}

#define MFMA16F(a, b, c) __builtin_amdgcn_mfma_f32_16x16x32_f16((a), (b), (c), 0, 0, 0)

// ============================ fp32 GEMM (enc3 only) ========================
__global__ __launch_bounds__(256, 2)
void gemm_bias_act(const float* __restrict__ A, const float* __restrict__ B,
                   const float* __restrict__ bias, float* __restrict__ C,
                   int M, int N, int K, int relu)
{
    __shared__ float as[BKT][LDA];   // as[k][m]
    __shared__ float bs[BKT][LDB];   // bs[k][n]
    const int tid = threadIdx.x;
    const int tx = tid & 15;
    const int ty = tid >> 4;
    const int row0 = blockIdx.y * BM;
    const int col0 = blockIdx.x * BN;

    const int ar = tid >> 2;             // 0..63
    const int ac = (tid & 3) << 2;       // 0,4,8,12
    const int br = tid >> 5;             // 0..7
    const int bc = (tid & 31) << 2;      // 0..124

    const float* Ap0 = A + (size_t)(row0 + ar) * K + ac;
    const float* Ap1 = A + (size_t)(row0 + ar + 64) * K + ac;
    const float* Bp0 = B + (size_t)br * N + col0 + bc;
    const float* Bp1 = B + (size_t)(br + 8) * N + col0 + bc;

    float acc[8][8];
#pragma unroll
    for (int i = 0; i < 8; ++i)
#pragma unroll
        for (int j = 0; j < 8; ++j) acc[i][j] = 0.f;

    for (int k0 = 0; k0 < K; k0 += BKT) {
        float4 a0 = *(const float4*)(Ap0 + k0);
        float4 a1 = *(const float4*)(Ap1 + k0);
        float4 b0 = *(const float4*)(Bp0 + (size_t)k0 * N);
        float4 b1 = *(const float4*)(Bp1 + (size_t)k0 * N);
        __syncthreads();
        as[ac + 0][ar] = a0.x; as[ac + 1][ar] = a0.y;
        as[ac + 2][ar] = a0.z; as[ac + 3][ar] = a0.w;
        as[ac + 0][ar + 64] = a1.x; as[ac + 1][ar + 64] = a1.y;
        as[ac + 2][ar + 64] = a1.z; as[ac + 3][ar + 64] = a1.w;
        *(float4*)&bs[br][bc] = b0;
        *(float4*)&bs[br + 8][bc] = b1;
        __syncthreads();
#pragma unroll
        for (int k = 0; k < BKT; ++k) {
            float af[8], bf0[4], bf1[4];
            *(float4*)&af[0] = *(const float4*)&as[k][ty * 8];
            *(float4*)&af[4] = *(const float4*)&as[k][ty * 8 + 4];
            *(float4*)&bf0[0] = *(const float4*)&bs[k][tx * 4];
            *(float4*)&bf1[0] = *(const float4*)&bs[k][64 + tx * 4];
#pragma unroll
            for (int i = 0; i < 8; ++i) {
#pragma unroll
                for (int j = 0; j < 4; ++j) {
                    acc[i][j]     = fmaf(af[i], bf0[j], acc[i][j]);
                    acc[i][j + 4] = fmaf(af[i], bf1[j], acc[i][j + 4]);
                }
            }
        }
    }

    float bv0[4], bv1[4];
#pragma unroll
    for (int j = 0; j < 4; ++j) {
        bv0[j] = bias[col0 + tx * 4 + j];
        bv1[j] = bias[col0 + 64 + tx * 4 + j];
    }
#pragma unroll
    for (int i = 0; i < 8; ++i) {
        const int row = row0 + ty * 8 + i;
        float4 o0, o1;
        o0.x = acc[i][0] + bv0[0]; o0.y = acc[i][1] + bv0[1];
        o0.z = acc[i][2] + bv0[2]; o0.w = acc[i][3] + bv0[3];
        o1.x = acc[i][4] + bv1[0]; o1.y = acc[i][5] + bv1[1];
        o1.z = acc[i][6] + bv1[2]; o1.w = acc[i][7] + bv1[3];
        if (relu) {
            o0.x = fmaxf(o0.x, 0.f); o0.y = fmaxf(o0.y, 0.f);
            o0.z = fmaxf(o0.z, 0.f); o0.w = fmaxf(o0.w, 0.f);
            o1.x = fmaxf(o1.x, 0.f); o1.y = fmaxf(o1.y, 0.f);
            o1.z = fmaxf(o1.z, 0.f); o1.w = fmaxf(o1.w, 0.f);
        }
        *(float4*)(C + (size_t)row * N + col0 + tx * 4) = o0;
        *(float4*)(C + (size_t)row * N + col0 + 64 + tx * 4) = o1;
    }
}

// ============================ VQ helpers ===================================
__global__ void cnorm_kernel(const float* __restrict__ CB, float* __restrict__ cnorm, int E)
{
    const int j = blockIdx.x;
    const float* c = CB + (size_t)j * E;
    float s = 0.f;
    for (int e = threadIdx.x; e < E; e += 64) { float v = c[e]; s += v * v; }
#pragma unroll
    for (int off = 32; off; off >>= 1) s += __shfl_down(s, off);
    if (threadIdx.x == 0) cnorm[j] = s;
}

__global__ void argmin_reduce(const float* __restrict__ partv, const int* __restrict__ parti,
                              int* __restrict__ idx, int M, int P)
{
    const int m = blockIdx.x * blockDim.x + threadIdx.x;
    if (m >= M) return;
    const float* pv = partv + (size_t)m * P;
    const int* pi = parti + (size_t)m * P;
    float best = pv[0]; int bi = pi[0];
    for (int t = 1; t < P; ++t) {
        float v = pv[t]; int ii = pi[t];
        if (v < best || (v == best && ii < bi)) { best = v; bi = ii; }
    }
    idx[m] = bi;
}

__global__ __launch_bounds__(256)
void vq_stats(const float* __restrict__ ZE, const float* __restrict__ CB,
              const int* __restrict__ idx, int* __restrict__ counts,
              float* __restrict__ vqaccum, int E)
{
    const int i = blockIdx.x;
    const int id = idx[i];
    const float* c = CB + (size_t)id * E;
    const float* z = ZE + (size_t)i * E;
    float s = 0.f;
    for (int e = threadIdx.x; e < E; e += 256) { float d = c[e] - z[e]; s += d * d; }
#pragma unroll
    for (int off = 32; off; off >>= 1) s += __shfl_down(s, off);
    __shared__ float red[4];
    const int lane = threadIdx.x & 63, w = threadIdx.x >> 6;
    if (lane == 0) red[w] = s;
    __syncthreads();
    if (threadIdx.x == 0) {
        atomicAdd(vqaccum, red[0] + red[1] + red[2] + red[3]);
        atomicAdd(counts + id, 1);
    }
}

__global__ void zero_kernel(int* __restrict__ p, int n)
{
    const int i = blockIdx.x * 256 + threadIdx.x;
    if (i < n) p[i] = 0;
}

__global__ __launch_bounds__(256)
void finalize(const int* __restrict__ counts, const float* __restrict__ vqaccum,
              float* __restrict__ tail, int NCODE, float invB, float scale)
{
    float s = 0.f;
    for (int j = threadIdx.x; j < NCODE; j += 256) {
        float p = (float)counts[j] * invB;
        s += p * logf(p + 1e-10f);
    }
#pragma unroll
    for (int off = 32; off; off >>= 1) s += __shfl_down(s, off);
    __shared__ float red[4];
    const int lane = threadIdx.x & 63, w = threadIdx.x >> 6;
    if (lane == 0) red[w] = s;
    __syncthreads();
    if (threadIdx.x == 0) {
        tail[0] = vqaccum[0] * scale;
        tail[1] = expf(-(red[0] + red[1] + red[2] + red[3]));
    }
}

// ============================ conversions ==================================
__global__ __launch_bounds__(256)
void transpose_bf16(const float* __restrict__ src, short* __restrict__ dst,
                    int Kd, int Nd)
{
    __shared__ float tile[32][33];
    const int bx = blockIdx.x * 32;   // N
    const int by = blockIdx.y * 32;   // K
    const int tx = threadIdx.x & 31, ty = threadIdx.x >> 5;
#pragma unroll
    for (int i = ty; i < 32; i += 8)
        tile[i][tx] = src[(size_t)(by + i) * Nd + bx + tx];
    __syncthreads();
#pragma unroll
    for (int i = ty; i < 32; i += 8)
        dst[(size_t)(bx + i) * Kd + by + tx] = f2bf(tile[tx][i]);
}

__global__ __launch_bounds__(256)
void transpose_split2(const float* __restrict__ src, half_t* __restrict__ dh,
                      half_t* __restrict__ dl, int Kd, int Nd)
{
    __shared__ float tile[32][33];
    const int bx = blockIdx.x * 32;   // N
    const int by = blockIdx.y * 32;   // K
    const int tx = threadIdx.x & 31, ty = threadIdx.x >> 5;
#pragma unroll
    for (int i = ty; i < 32; i += 8)
        tile[i][tx] = src[(size_t)(by + i) * Nd + bx + tx];
    __syncthreads();
#pragma unroll
    for (int i = ty; i < 32; i += 8) {
        float v = tile[tx][i];
        half_t h, l; fsplit(v, h, l);
        dh[(size_t)(bx + i) * Kd + by + tx] = h;
        dl[(size_t)(bx + i) * Kd + by + tx] = l;
    }
}

__global__ void convert_bf16_vec(const float* __restrict__ src, short* __restrict__ dst, int n4)
{
    const int i = blockIdx.x * 256 + threadIdx.x;
    if (i >= n4) return;
    float4 v = ((const float4*)src)[i];
    short4 o;
    o.x = f2bf(v.x); o.y = f2bf(v.y); o.z = f2bf(v.z); o.w = f2bf(v.w);
    ((short4*)dst)[i] = o;
}

__global__ void split2_vec(const float* __restrict__ src, half_t* __restrict__ hi,
                           half_t* __restrict__ lo, int n4)
{
    const int i = blockIdx.x * 256 + threadIdx.x;
    if (i >= n4) return;
    float4 v = ((const float4*)src)[i];
    f16x4 h, l;
    h[0] = (half_t)v.x; l[0] = (half_t)((v.x - (float)h[0]) * LO_SCALE);
    h[1] = (half_t)v.y; l[1] = (half_t)((v.y - (float)h[1]) * LO_SCALE);
    h[2] = (half_t)v.z; l[2] = (half_t)((v.z - (float)h[2]) * LO_SCALE);
    h[3] = (half_t)v.w; l[3] = (half_t)((v.w - (float)h[3]) * LO_SCALE);
    ((f16x4*)hi)[i] = h;
    ((f16x4*)lo)[i] = l;
}

// ===================== double-f16 MFMA GEMM, BK=64 =========================
// C = A[M,K] @ BT[N,K]^T, fp32-class via Dekker limbs:
//   acc_h += ah*bh ; acc_c += ah*bl + al*bh ; result = acc_h + acc_c*2^-12
// LDS per plane: sliced [2][128][32] halfs (16 KiB) -> row stride 64 B keeps
// the proven conflict-free read geometry. Staging: physical chunk p=v*256+t
// (linear dest); source addr carries the slice permutation:
//   p -> slice=p>>9, row=(p>>2)&127, cc=p&3 ; src k-off = slice*32 + cc*8.
// One barrier pair per K=64 (2x MFMA work per drain vs BK=32).
// MODE 0: fp32 out Cf (+bias).  MODE 1: bias+ReLU, split f16 pair out.
template<int MODE>
__global__ __launch_bounds__(256, 2)
void gemm_f16x2(const half_t* __restrict__ Ah, const half_t* __restrict__ Al,
                const half_t* __restrict__ Bh, const half_t* __restrict__ Bl,
                const float* __restrict__ bias, float* __restrict__ Cf,
                half_t* __restrict__ Ch, half_t* __restrict__ Cl,
                int N, int K)
{
    __shared__ half_t sAh[8192], sAl[8192], sBh[8192], sBl[8192];   // 64 KiB
    const int t = threadIdx.x;
    const int lane = t & 63, wave = t >> 6;
    const int rh = (wave >> 1) * 64, ch = (wave & 1) * 64;
    const int ml = lane & 15, quad = lane >> 4;
    const int row0 = blockIdx.y * 128, col0 = blockIdx.x * 128;

    size_t offA[4], offB[4];
#pragma unroll
    for (int v = 0; v < 4; ++v) {
        const int p = v * 256 + t;
        const int slice = p >> 9, row = (p >> 2) & 127, cc = p & 3;
        offA[v] = (size_t)(row0 + row) * K + slice * 32 + cc * 8;
        offB[v] = (size_t)(col0 + row) * K + slice * 32 + cc * 8;
    }
    const int dst = t * 8;            // halfs; + v*2048 per v

    floatx4 acc_h[4][4] = {};
    floatx4 acc_c[4][4] = {};

    for (int k0 = 0; k0 < K; k0 += 64) {
        __syncthreads();
#pragma unroll
        for (int v = 0; v < 4; ++v) {
            gload16(Ah + offA[v] + k0, sAh + v * 2048 + dst);
            gload16(Al + offA[v] + k0, sAl + v * 2048 + dst);
            gload16(Bh + offB[v] + k0, sBh + v * 2048 + dst);
            gload16(Bl + offB[v] + k0, sBl + v * 2048 + dst);
        }
        __syncthreads();
#pragma unroll
        for (int s = 0; s < 2; ++s) {
            f16x8 ah[4], alo[4], bh[4], blo[4];
#pragma unroll
            for (int i = 0; i < 4; ++i) {
                ah[i]  = *(const f16x8*)(sAh + s * 4096 + (rh + i * 16 + ml) * 32 + quad * 8);
                alo[i] = *(const f16x8*)(sAl + s * 4096 + (rh + i * 16 + ml) * 32 + quad * 8);
            }
#pragma unroll
            for (int j = 0; j < 4; ++j) {
                bh[j]  = *(const f16x8*)(sBh + s * 4096 + (ch + j * 16 + ml) * 32 + quad * 8);
                blo[j] = *(const f16x8*)(sBl + s * 4096 + (ch + j * 16 + ml) * 32 + quad * 8);
            }
#pragma unroll
            for (int i = 0; i < 4; ++i)
#pragma unroll
                for (int j = 0; j < 4; ++j) {
                    acc_h[i][j] = MFMA16F(ah[i],  bh[j],  acc_h[i][j]);
                    acc_c[i][j] = MFMA16F(ah[i],  blo[j], acc_c[i][j]);
                    acc_c[i][j] = MFMA16F(alo[i], bh[j],  acc_c[i][j]);
                }
        }
    }

    float bv[4];
#pragma unroll
    for (int j = 0; j < 4; ++j) bv[j] = bias[col0 + ch + j * 16 + ml];
#pragma unroll
    for (int i = 0; i < 4; ++i)
#pragma unroll
        for (int j = 0; j < 4; ++j) {
            const int col = col0 + ch + j * 16 + ml;
#pragma unroll
            for (int reg = 0; reg < 4; ++reg) {
                const int row = row0 + rh + i * 16 + quad * 4 + reg;
                float v = fmaf(acc_c[i][j][reg], LO_INV, acc_h[i][j][reg]) + bv[j];
                if (MODE == 0) {
                    Cf[(size_t)row * N + col] = v;
                } else {
                    v = fmaxf(v, 0.f);
                    half_t hh = (half_t)v;
                    Ch[(size_t)row * N + col] = hh;
                    Cl[(size_t)row * N + col] = (half_t)((v - (float)hh) * LO_SCALE);
                }
            }
        }
}

// VQ distance + fused partial argmin, BK=64. score_j = ||c_j||^2 - 2*(ze.c_j)
__global__ __launch_bounds__(256, 2)
void dist_f16x2_argmin(const half_t* __restrict__ Ah, const half_t* __restrict__ Al,
                       const half_t* __restrict__ Bh, const half_t* __restrict__ Bl,
                       const float* __restrict__ cnorm, float* __restrict__ partv,
                       int* __restrict__ parti, int K)
{
    __shared__ half_t smem[32768];                 // 64 KiB
    half_t* sAh = smem;
    half_t* sAl = smem + 8192;
    half_t* sBh = smem + 16384;
    half_t* sBl = smem + 24576;

    const int t = threadIdx.x;
    const int lane = t & 63, wave = t >> 6;
    const int rh = (wave >> 1) * 64, ch = (wave & 1) * 64;
    const int ml = lane & 15, quad = lane >> 4;
    const int row0 = blockIdx.y * 128, col0 = blockIdx.x * 128;

    size_t offA[4], offB[4];
#pragma unroll
    for (int v = 0; v < 4; ++v) {
        const int p = v * 256 + t;
        const int slice = p >> 9, row = (p >> 2) & 127, cc = p & 3;
        offA[v] = (size_t)(row0 + row) * K + slice * 32 + cc * 8;
        offB[v] = (size_t)(col0 + row) * K + slice * 32 + cc * 8;
    }
    const int dst = t * 8;

    floatx4 acc_h[4][4] = {};
    floatx4 acc_c[4][4] = {};

    for (int k0 = 0; k0 < K; k0 += 64) {
        __syncthreads();
#pragma unroll
        for (int v = 0; v < 4; ++v) {
            gload16(Ah + offA[v] + k0, sAh + v * 2048 + dst);
            gload16(Al + offA[v] + k0, sAl + v * 2048 + dst);
            gload16(Bh + offB[v] + k0, sBh + v * 2048 + dst);
            gload16(Bl + offB[v] + k0, sBl + v * 2048 + dst);
        }
        __syncthreads();
#pragma unroll
        for (int s = 0; s < 2; ++s) {
            f16x8 ah[4], alo[4], bh[4], blo[4];
#pragma unroll
            for (int i = 0; i < 4; ++i) {
                ah[i]  = *(const f16x8*)(sAh + s * 4096 + (rh + i * 16 + ml) * 32 + quad * 8);
                alo[i] = *(const f16x8*)(sAl + s * 4096 + (rh + i * 16 + ml) * 32 + quad * 8);
            }
#pragma unroll
            for (int j = 0; j < 4; ++j) {
                bh[j]  = *(const f16x8*)(sBh + s * 4096 + (ch + j * 16 + ml) * 32 + quad * 8);
                blo[j] = *(const f16x8*)(sBl + s * 4096 + (ch + j * 16 + ml) * 32 + quad * 8);
            }
#pragma unroll
            for (int i = 0; i < 4; ++i)
#pragma unroll
                for (int j = 0; j < 4; ++j) {
                    acc_h[i][j] = MFMA16F(ah[i],  bh[j],  acc_h[i][j]);
                    acc_c[i][j] = MFMA16F(ah[i],  blo[j], acc_c[i][j]);
                    acc_c[i][j] = MFMA16F(alo[i], bh[j],  acc_c[i][j]);
                }
        }
    }

    float cnv[4];
#pragma unroll
    for (int j = 0; j < 4; ++j) cnv[j] = cnorm[col0 + ch + j * 16 + ml];

    __syncthreads();                   // alias staging LDS for the reduction
    float* rv = (float*)smem;          // [128][32] = 16 KiB
    int*   ri = (int*)(smem + 8192);   // [128][32] = 16 KiB (byte off 16384)
    const int slot = (wave & 1) * 16 + ml;

#pragma unroll
    for (int i = 0; i < 4; ++i) {
#pragma unroll
        for (int reg = 0; reg < 4; ++reg) {
            const int lr = rh + i * 16 + quad * 4 + reg;
            float best = __builtin_inff(); int bi = 0;
#pragma unroll
            for (int j = 0; j < 4; ++j) {   // cols ascend with j -> strict <
                float s = fmaf(acc_c[i][j][reg], LO_INV, acc_h[i][j][reg]);
                float v = cnv[j] - 2.f * s;
                if (v < best) { best = v; bi = col0 + ch + j * 16 + ml; }
            }
            rv[lr * 32 + slot] = best;
            ri[lr * 32 + slot] = bi;
        }
    }
    __syncthreads();
    if (t < 128) {
        float best = __builtin_inff(); int bi = 0x7fffffff;
        for (int s = 0; s < 32; ++s) {
            const int sl = (s + t) & 31;   // rotated -> conflict-free
            float v = rv[t * 32 + sl]; int ii = ri[t * 32 + sl];
            if (v < best || (v == best && ii < bi)) { best = v; bi = ii; }
        }
        partv[(size_t)(row0 + t) * gridDim.x + blockIdx.x] = best;
        parti[(size_t)(row0 + t) * gridDim.x + blockIdx.x] = bi;
    }
}

// ===================== bf16 MFMA GEMM (decoder), BK=64 =====================
template<int RELU, int OUT_BF16, int GATHER>
__global__ __launch_bounds__(256)
void mfma_gemm_bt(const short* __restrict__ A, const short* __restrict__ BT,
                  const float* __restrict__ bias, float* __restrict__ Cf,
                  short* __restrict__ Cb, int M, int N, int K,
                  const int* __restrict__ rowidx)
{
    __shared__ short sA[8192];   // [2][128][32] = 16 KiB
    __shared__ short sB[8192];
    const int t = threadIdx.x;
    const int lane = t & 63;
    const int wave = t >> 6;
    const int rh = (wave >> 1) * 64;
    const int ch = (wave & 1) * 64;
    const int ml = lane & 15;
    const int quad = lane >> 4;
    const int row0 = blockIdx.y * 128, col0 = blockIdx.x * 128;

    size_t offA[4], offB[4];
#pragma unroll
    for (int v = 0; v < 4; ++v) {
        const int p = v * 256 + t;
        const int slice = p >> 9, row = (p >> 2) & 127, cc = p & 3;
        int ga = row0 + row;
        if (GATHER) ga = rowidx[ga];
        offA[v] = (size_t)ga * K + slice * 32 + cc * 8;
        offB[v] = (size_t)(col0 + row) * K + slice * 32 + cc * 8;
    }
    const int dst = t * 8;

    floatx4 acc[4][4] = {};

    for (int k0 = 0; k0 < K; k0 += 64) {
        __syncthreads();
#pragma unroll
        for (int v = 0; v < 4; ++v) {
            gload16(A + offA[v] + k0, sA + v * 2048 + dst);
            gload16(BT + offB[v] + k0, sB + v * 2048 + dst);
        }
        __syncthreads();
#pragma unroll
        for (int s = 0; s < 2; ++s) {
            bf16x8 af[4], bf[4];
#pragma unroll
            for (int i = 0; i < 4; ++i)
                af[i] = *(const bf16x8*)(sA + s * 4096 + (rh + i * 16 + ml) * 32 + quad * 8);
#pragma unroll
            for (int j = 0; j < 4; ++j)
                bf[j] = *(const bf16x8*)(sB + s * 4096 + (ch + j * 16 + ml) * 32 + quad * 8);
#pragma unroll
            for (int i = 0; i < 4; ++i)
#pragma unroll
                for (int j = 0; j < 4; ++j)
                    acc[i][j] = __builtin_amdgcn_mfma_f32_16x16x32_bf16(
                        af[i], bf[j], acc[i][j], 0, 0, 0);
        }
    }

    float bv[4];
#pragma unroll
    for (int j = 0; j < 4; ++j) bv[j] = bias[col0 + ch + j * 16 + ml];
#pragma unroll
    for (int i = 0; i < 4; ++i) {
#pragma unroll
        for (int j = 0; j < 4; ++j) {
            const int col = col0 + ch + j * 16 + ml;
#pragma unroll
            for (int reg = 0; reg < 4; ++reg) {
                const int row = row0 + rh + i * 16 + quad * 4 + reg;
                float v = acc[i][j][reg] + bv[j];
                if (RELU) v = fmaxf(v, 0.f);
                if (OUT_BF16) Cb[(size_t)row * N + col] = f2bf(v);
                else          Cf[(size_t)row * N + col] = v;
            }
        }
    }
}

// ============================ launch =======================================
extern "C" void kernel_launch(void* const* d_in, const int* in_sizes, int n_in,
                              void* d_out, int out_size, void* d_ws, size_t ws_size,
                              hipStream_t stream)
{
    const float* x      = (const float*)d_in[0];
    const float* enc_w1 = (const float*)d_in[1];
    const float* enc_b1 = (const float*)d_in[2];
    const float* enc_w2 = (const float*)d_in[3];
    const float* enc_b2 = (const float*)d_in[4];
    const float* pre_w  = (const float*)d_in[5];
    const float* pre_b  = (const float*)d_in[6];
    const float* cb     = (const float*)d_in[7];
    const float* dec_w1 = (const float*)d_in[8];
    const float* dec_b1 = (const float*)d_in[9];
    const float* dec_w2 = (const float*)d_in[10];
    const float* dec_b2 = (const float*)d_in[11];
    float* out = (float*)d_out;

    const int B = 8192, X = 4096, H = 4096, Z = 512, E = 512, NC = 8192;

    // Workspace map (peak 200 MiB) with lifetime aliasing (same as R4):
    //   [0,128Mi):    xh/xl (until enc1)   -> then z, ze, zeh/zel, cbh/cbl,
    //                                          hd_bf
    //   [128,192Mi):  w1Th/w1Tl (enc1)     -> then dw1T, dw2T, cb_bf
    //   [192,200Mi):  w2Th/w2Tl (enc2)     -> then cn, pv, pi, idx, cnt, vqa
    //   hhp/hlp (enc1 out, 128 MiB) live on d_out (dead until dec2 writes
    //   x_recon at the very end; enc1 fully rewrites before enc2 reads).
    char* w = (char*)d_ws;
    half_t* xh   = (half_t*)(w);                      // 64 MiB
    half_t* xl   = (half_t*)(w + 67108864ull);        // 64 MiB
    half_t* w1Th = (half_t*)(w + 134217728ull);       // 32 MiB
    half_t* w1Tl = (half_t*)(w + 167772160ull);       // 32 MiB
    half_t* w2Th = (half_t*)(w + 201326592ull);       // 4 MiB
    half_t* w2Tl = (half_t*)(w + 205520896ull);       // 4 MiB  (peak 200 MiB)

    half_t* hhp  = (half_t*)d_out;                    // 64 MiB (on out)
    half_t* hlp  = (half_t*)((char*)d_out + 67108864ull); // 64 MiB (on out)

    float*  z    = (float*)(w);                       // 16 MiB (post-enc1)
    float*  ze   = (float*)(w + 16777216ull);         // 16 MiB
    half_t* zeh  = (half_t*)(w + 33554432ull);        // 8 MiB
    half_t* zel  = (half_t*)(w + 41943040ull);        // 8 MiB
    half_t* cbh  = (half_t*)(w + 50331648ull);        // 8 MiB
    half_t* cbl  = (half_t*)(w + 58720256ull);        // 8 MiB  -> 64 MiB
    short*  hd_bf= (short*)(w + 67108864ull);         // 64 MiB (post-enc1, xl)

    short*  dw1T = (short*)(w + 134217728ull);        // 4 MiB (post-enc1, w1T)
    short*  dw2T = (short*)(w + 138412032ull);        // 32 MiB
    short*  cb_bf= (short*)(w + 171966464ull);        // 8 MiB -> ends 180 MiB

    float*  cn   = (float*)(w + 201326592ull);        // 32 KiB (post-enc2, w2T)
    float*  pv   = (float*)(w + 201359360ull);        // 2 MiB (B*64)
    int*    pi   = (int*)  (w + 203456512ull);        // 2 MiB
    int*    idx  = (int*)  (w + 205553664ull);        // 32 KiB
    int*    cnt  = (int*)  (w + 205586432ull);        // 32 KiB
    float*  vqa  = (float*)(w + 205619200ull);        // 4 B

    dim3 blk(256);

    // input/weight prep: transpose + f16 limb split
    split2_vec<<<(B * X / 4 + 255) / 256, blk, 0, stream>>>(x, xh, xl, B * X / 4);
    transpose_split2<<<dim3(H / 32, X / 32), blk, 0, stream>>>(enc_w1, w1Th, w1Tl, X, H);
    transpose_split2<<<dim3(Z / 32, H / 32), blk, 0, stream>>>(enc_w2, w2Th, w2Tl, H, Z);

    // encoder (double-f16 MFMA; fp32-class precision), BK=64
    gemm_f16x2<1><<<dim3(H / 128, B / 128), blk, 0, stream>>>(
        xh, xl, w1Th, w1Tl, enc_b1, nullptr, hhp, hlp, H, X);
    gemm_f16x2<0><<<dim3(Z / 128, B / 128), blk, 0, stream>>>(
        hhp, hlp, w2Th, w2Tl, enc_b2, z, nullptr, nullptr, Z, H);
    gemm_bias_act<<<dim3(E / BN, B / BM), blk, 0, stream>>>(z, pre_w, pre_b, ze, B, E, Z, 0);

    // VQ (double-f16 distances, exact fp32 cnorm, fused partial argmin)
    split2_vec<<<(B * E / 4 + 255) / 256, blk, 0, stream>>>(ze, zeh, zel, B * E / 4);
    split2_vec<<<(NC * E / 4 + 255) / 256, blk, 0, stream>>>(cb, cbh, cbl, NC * E / 4);
    cnorm_kernel<<<NC, 64, 0, stream>>>(cb, cn, E);
    zero_kernel<<<(NC + 1 + 255) / 256, blk, 0, stream>>>(cnt, NC + 1);
    dist_f16x2_argmin<<<dim3(NC / 128, B / 128), blk, 0, stream>>>(
        zeh, zel, cbh, cbl, cn, pv, pi, E);
    argmin_reduce<<<B / 256, blk, 0, stream>>>(pv, pi, idx, B, NC / 128);
    vq_stats<<<B, blk, 0, stream>>>(ze, cb, idx, cnt, vqa, E);

    // decoder (bf16 MFMA, BK=64); weight prep after enc2 frees regions
    convert_bf16_vec<<<(NC * E / 4 + 255) / 256, blk, 0, stream>>>(cb, cb_bf, NC * E / 4);
    transpose_bf16<<<dim3(H / 32, E / 32), blk, 0, stream>>>(dec_w1, dw1T, E, H);
    transpose_bf16<<<dim3(X / 32, H / 32), blk, 0, stream>>>(dec_w2, dw2T, H, X);
    mfma_gemm_bt<1, 1, 1><<<dim3(H / 128, B / 128), blk, 0, stream>>>(
        cb_bf, dw1T, dec_b1, nullptr, hd_bf, B, H, E, idx);
    mfma_gemm_bt<0, 0, 0><<<dim3(X / 128, B / 128), blk, 0, stream>>>(
        hd_bf, dw2T, dec_b2, out, nullptr, B, X, H, nullptr);

    finalize<<<1, blk, 0, stream>>>(cnt, vqa, out + (out_size - 2), NC,
                                    1.f / (float)B, 1.25f / ((float)B * (float)E));
}